// Round 1
// baseline (14.574 us; speedup 1.0000x reference)
//
#include <hip/hip_runtime.h>

namespace {

constexpr int B = 4096;
constexpr int F = 256;
constexpr int H = 32;
constexpr int FT = 64;      // features per block (lane -> feature, coalesced)
constexpr int NB = 4;       // batch rows per thread
constexpr int GROUPS = 4;   // 256 threads / 64 lanes-of-features
constexpr int BT = GROUPS * NB;  // batch rows per block = 16
constexpr int FTP = FT + 1;      // LDS pad -> conflict-free
constexpr float NEG_LOG2E = -1.44269504088896340736f;
constexpr float LOG2_0P1  = -3.32192809488736234787f;  // log2(0.1)

__global__ __launch_bounds__(256, 4) void convex_kernel(
    const float* __restrict__ inputs,
    const float* __restrict__ k,
    const float* __restrict__ W1,
    const float* __restrict__ b1,
    const float* __restrict__ W2,
    const float* __restrict__ b2,
    float* __restrict__ out)
{
  __shared__ float sW1a[H][FTP];  // -W1[f,0,j]
  __shared__ float sC[H][FTP];    // -log2e * (k[f]*W1[f,1,j] + b1[f,j])
  __shared__ float sW2[H][FTP];   // W2[f,j]
  __shared__ float sB2[FT];

  const int nfb = F / FT;                // 4
  const int fb = blockIdx.x % nfb;
  const int bb = blockIdx.x / nfb;
  const int f0 = fb * FT;
  const int b0 = bb * BT;

  // Stage & pre-fold params. idx -> (fl = idx/32, j = idx%32): half-wave reads
  // 32 consecutive floats of W1 (coalesced-ish, L2-resident anyway); LDS write
  // addr = (j*65 + fl)*4 -> banks j*65 % 32 = j%32, conflict-free.
  for (int idx = threadIdx.x; idx < FT * H; idx += 256) {
    const int fl = idx >> 5;
    const int j  = idx & (H - 1);
    const int f  = f0 + fl;
    const float kf = k[f];
    sW1a[j][fl] = -W1[(f * 2 + 0) * H + j];
    sC[j][fl]   = NEG_LOG2E * fmaf(kf, W1[(f * 2 + 1) * H + j], b1[f * H + j]);
    sW2[j][fl]  = W2[f * H + j];
  }
  if (threadIdx.x < FT) sB2[threadIdx.x] = b2[f0 + threadIdx.x];
  __syncthreads();

  const int fl = threadIdx.x & 63;
  const int g  = threadIdx.x >> 6;
  const int f  = f0 + fl;
  const float b2f = sB2[fl];

  float na[NB], used[NB], acc[NB];
#pragma unroll
  for (int i = 0; i < NB; ++i) {
    const int b = b0 + g * NB + i;
    const float x = inputs[b * F + f];     // 64 lanes -> 256B contiguous
    used[i] = (x > -0.5f) ? 1.0f : 0.0f;
    // na2 = log2(0.1/x); reference na = ln(0.1/x) = ln2 * na2 (folded below)
    float n = LOG2_0P1 - __builtin_amdgcn_logf(x);
    if (n != n) n = 0.0f;                  // log_filter_nan: NaN (x<0) -> 0
    na[i] = n;
    acc[i] = 0.0f;
  }

  // z2 = -log2e*(na*W1a + c) = na2*(-W1a) + (-log2e*c); sigmoid = rcp(1+2^z2)
#pragma unroll
  for (int j = 0; j < H; ++j) {
    const float w1 = sW1a[j][fl];
    const float c  = sC[j][fl];
    const float w2 = sW2[j][fl];
#pragma unroll
    for (int i = 0; i < NB; ++i) {
      const float z2 = fmaf(na[i], w1, c);
      const float e  = __builtin_amdgcn_exp2f(z2);
      const float s  = __builtin_amdgcn_rcpf(1.0f + e);
      acc[i] = fmaf(s, w2, acc[i]);
    }
  }

#pragma unroll
  for (int i = 0; i < NB; ++i) {
    const int b = b0 + g * NB + i;
    out[b * F + f] = (acc[i] + b2f) * used[i];
  }
}

}  // namespace

extern "C" void kernel_launch(void* const* d_in, const int* in_sizes, int n_in,
                              void* d_out, int out_size, void* d_ws, size_t ws_size,
                              hipStream_t stream) {
  const float* inputs = (const float*)d_in[0];
  // d_in[1] = noise: unused — the reference's return value (h_out) does not
  // depend on it (h_higher/h_lower are discarded).
  const float* k  = (const float*)d_in[2];
  const float* W1 = (const float*)d_in[3];
  const float* b1 = (const float*)d_in[4];
  const float* W2 = (const float*)d_in[5];
  const float* b2 = (const float*)d_in[6];
  float* out = (float*)d_out;

  dim3 grid((F / FT) * (B / BT));   // 4 * 256 = 1024 blocks
  dim3 block(256);
  hipLaunchKernelGGL(convex_kernel, grid, block, 0, stream,
                     inputs, k, W1, b1, W2, b2, out);
}

// Round 2
// 13.407 us; speedup vs baseline: 1.0871x; 1.0871x over previous
//
#include <hip/hip_runtime.h>

namespace {

typedef float v2f __attribute__((ext_vector_type(2)));

constexpr int B = 4096;
constexpr int F = 256;
constexpr int H = 32;
constexpr int FT = 64;      // features per block (lane -> feature, coalesced)
constexpr int NB = 8;       // batch rows per thread (8 independent chains)
constexpr int NP = NB / 2;  // float2 pairs
constexpr int GROUPS = 4;   // 256 threads / 64 lanes-of-features
constexpr int BT = GROUPS * NB;  // batch rows per block = 32
constexpr int FTP = FT + 1;      // LDS pad -> conflict-free
constexpr float NEG_LOG2E = -1.44269504088896340736f;
constexpr float LOG2_0P1  = -3.32192809488736234787f;  // log2(0.1)

__global__ __launch_bounds__(256, 2) void convex_kernel(
    const float* __restrict__ inputs,
    const float* __restrict__ k,
    const float* __restrict__ W1,
    const float* __restrict__ b1,
    const float* __restrict__ W2,
    const float* __restrict__ b2,
    float* __restrict__ out)
{
  __shared__ float sW1a[H][FTP];  // -W1[f,0,j]
  __shared__ float sC[H][FTP];    // -log2e * (k[f]*W1[f,1,j] + b1[f,j])
  __shared__ float sW2[H][FTP];   // W2[f,j]
  __shared__ float sB2[FT];

  const int nfb = F / FT;                // 4
  const int fb = blockIdx.x % nfb;
  const int bb = blockIdx.x / nfb;
  const int f0 = fb * FT;
  const int b0 = bb * BT;

  // Stage & pre-fold params (tiny: 6K floats, L2/L3-resident).
  for (int idx = threadIdx.x; idx < FT * H; idx += 256) {
    const int fl = idx >> 5;
    const int j  = idx & (H - 1);
    const int f  = f0 + fl;
    const float kf = k[f];
    sW1a[j][fl] = -W1[(f * 2 + 0) * H + j];
    sC[j][fl]   = NEG_LOG2E * fmaf(kf, W1[(f * 2 + 1) * H + j], b1[f * H + j]);
    sW2[j][fl]  = W2[f * H + j];
  }
  if (threadIdx.x < FT) sB2[threadIdx.x] = b2[f0 + threadIdx.x];
  __syncthreads();

  const int fl = threadIdx.x & 63;
  const int g  = threadIdx.x >> 6;
  const int f  = f0 + fl;
  const float b2f = sB2[fl];

  v2f nav[NP], usedv[NP], accv[NP];
#pragma unroll
  for (int i = 0; i < NB; ++i) {
    const int b = b0 + g * NB + i;
    const float x = inputs[b * F + f];     // 64 lanes -> 256B contiguous
    // na2 = log2(0.1/x); reference na = ln(0.1/x) = ln2 * na2 (folded into sC)
    float n = LOG2_0P1 - __builtin_amdgcn_logf(x);
    if (n != n) n = 0.0f;                  // log_filter_nan: NaN (x<0) -> 0
    nav[i >> 1][i & 1]  = n;
    usedv[i >> 1][i & 1] = (x > -0.5f) ? 1.0f : 0.0f;
    accv[i >> 1][i & 1] = 0.0f;
  }

  // z2 = na2*(-W1a) + (-log2e*(k*W1b+b1)); sigmoid = rcp(1 + 2^z2)
#pragma unroll
  for (int j = 0; j < H; ++j) {
    const float w1 = sW1a[j][fl];
    const float c  = sC[j][fl];
    const float w2 = sW2[j][fl];
    const v2f w1v = {w1, w1};
    const v2f cv  = {c, c};
    const v2f w2v = {w2, w2};
#pragma unroll
    for (int p = 0; p < NP; ++p) {
      v2f z2 = __builtin_elementwise_fma(nav[p], w1v, cv);  // v_pk_fma_f32
      v2f e;
      e.x = __builtin_amdgcn_exp2f(z2.x);
      e.y = __builtin_amdgcn_exp2f(z2.y);
      v2f t = e + (v2f){1.0f, 1.0f};                        // v_pk_add_f32
      v2f s;
      s.x = __builtin_amdgcn_rcpf(t.x);
      s.y = __builtin_amdgcn_rcpf(t.y);
      accv[p] = __builtin_elementwise_fma(s, w2v, accv[p]); // v_pk_fma_f32
    }
  }

#pragma unroll
  for (int i = 0; i < NB; ++i) {
    const int b = b0 + g * NB + i;
    out[b * F + f] = (accv[i >> 1][i & 1] + b2f) * usedv[i >> 1][i & 1];
  }
}

}  // namespace

extern "C" void kernel_launch(void* const* d_in, const int* in_sizes, int n_in,
                              void* d_out, int out_size, void* d_ws, size_t ws_size,
                              hipStream_t stream) {
  const float* inputs = (const float*)d_in[0];
  // d_in[1] = noise: unused — the reference's return value (h_out) does not
  // depend on it (h_higher/h_lower are discarded).
  const float* k  = (const float*)d_in[2];
  const float* W1 = (const float*)d_in[3];
  const float* b1 = (const float*)d_in[4];
  const float* W2 = (const float*)d_in[5];
  const float* b2 = (const float*)d_in[6];
  float* out = (float*)d_out;

  dim3 grid((F / FT) * (B / BT));   // 4 * 128 = 512 blocks (2 per CU)
  dim3 block(256);
  hipLaunchKernelGGL(convex_kernel, grid, block, 0, stream,
                     inputs, k, W1, b1, W2, b2, out);
}